// Round 12
// baseline (404.229 us; speedup 1.0000x reference)
//
#include <hip/hip_runtime.h>
#include <math.h>

#define LL 1024
#define DD 512
#define NB 16

typedef __attribute__((ext_vector_type(8))) short bf16x8;
typedef __attribute__((ext_vector_type(4))) float f32x4;
typedef unsigned short u16;
typedef unsigned int u32;
typedef const __attribute__((address_space(1))) void* gptr_t;
typedef __attribute__((address_space(3))) void* sptr_t;

static const long NLD = (long)NB * LL * DD;  // 8,388,608
static const long NLL = (long)NB * LL * LL;  // 16,777,216

__device__ __forceinline__ u16 f2bf(float x) {
  u32 u = __float_as_uint(x);
  u += 0x7fffu + ((u >> 16) & 1u);
  return (u16)(u >> 16);
}
__device__ __forceinline__ float bf2f(u16 h) {
  return __uint_as_float((u32)h << 16);
}

// XCD-chunked bijective remap (grids multiple of 128): 16-chunk per XCD.
__device__ __forceinline__ int xcd_chunk16(int flat) {
  const int j = flat >> 3;
  return ((j >> 4) << 7) + ((flat & 7) << 4) + (j & 15);
}

// ---------------------------------------------------------------------------
// q/k/v -> bf16 hi(+lo). z: 0=q(split) 1=k(split) 2=v(plain)
// ---------------------------------------------------------------------------
__global__ __launch_bounds__(256) void k_split3(
    const float* __restrict__ q, const float* __restrict__ k,
    const float* __restrict__ v, u16* __restrict__ qh, u16* __restrict__ ql,
    u16* __restrict__ kh, u16* __restrict__ kl, u16* __restrict__ vh) {
  const int z = blockIdx.z;
  const float* x = (z == 0) ? q : (z == 1) ? k : v;
  u16* hi = (z == 0) ? qh : (z == 1) ? kh : vh;
  u16* lo = (z == 0) ? ql : kl;
  const long stride = (long)gridDim.x * 1024;
  for (long i = ((long)blockIdx.x * 256 + threadIdx.x) * 4; i < NLD;
       i += stride) {
    const float4 vv = *(const float4*)(x + i);
    ushort4 h;
    h.x = f2bf(vv.x);
    h.y = f2bf(vv.y);
    h.z = f2bf(vv.z);
    h.w = f2bf(vv.w);
    *(ushort4*)(hi + i) = h;
    if (z < 2) {
      ushort4 s;
      s.x = f2bf(vv.x - bf2f(h.x));
      s.y = f2bf(vv.y - bf2f(h.y));
      s.z = f2bf(vv.z - bf2f(h.z));
      s.w = f2bf(vv.w - bf2f(h.w));
      *(ushort4*)(lo + i) = s;
    }
  }
}

// dist -> split bf16
__global__ __launch_bounds__(256) void k_splitd(const float* __restrict__ x,
                                                u16* __restrict__ hi,
                                                u16* __restrict__ lo) {
  const long stride = (long)gridDim.x * 1024;
  for (long i = ((long)blockIdx.x * 256 + threadIdx.x) * 4; i < NLL;
       i += stride) {
    const float4 v = *(const float4*)(x + i);
    ushort4 h, s;
    h.x = f2bf(v.x);
    h.y = f2bf(v.y);
    h.z = f2bf(v.z);
    h.w = f2bf(v.w);
    s.x = f2bf(v.x - bf2f(h.x));
    s.y = f2bf(v.y - bf2f(h.y));
    s.z = f2bf(v.z - bf2f(h.z));
    s.w = f2bf(v.w - bf2f(h.w));
    *(ushort4*)(hi + i) = h;
    *(ushort4*)(lo + i) = s;
  }
}

// all 6 weights. z: 0..3 plain (Wq,Wk,Wv,Wfc), 4..5 split (Wqt,Wkt)
__global__ __launch_bounds__(256) void k_splitw(
    const float* __restrict__ Wq, const float* __restrict__ Wk,
    const float* __restrict__ Wv, const float* __restrict__ Wfc,
    const float* __restrict__ Wqt, const float* __restrict__ Wkt,
    u16* __restrict__ Wq_h, u16* __restrict__ Wk_h, u16* __restrict__ Wv_h,
    u16* __restrict__ Wfc_h, u16* __restrict__ Wqt_h,
    u16* __restrict__ Wqt_l, u16* __restrict__ Wkt_h,
    u16* __restrict__ Wkt_l) {
  const int z = blockIdx.z;
  const float* x;
  u16 *hi, *lo = nullptr;
  switch (z) {
    case 0: x = Wq; hi = Wq_h; break;
    case 1: x = Wk; hi = Wk_h; break;
    case 2: x = Wv; hi = Wv_h; break;
    case 3: x = Wfc; hi = Wfc_h; break;
    case 4: x = Wqt; hi = Wqt_h; lo = Wqt_l; break;
    default: x = Wkt; hi = Wkt_h; lo = Wkt_l; break;
  }
  const long i = ((long)blockIdx.x * 256 + threadIdx.x) * 4;
  const float4 v = *(const float4*)(x + i);
  ushort4 h;
  h.x = f2bf(v.x);
  h.y = f2bf(v.y);
  h.z = f2bf(v.z);
  h.w = f2bf(v.w);
  *(ushort4*)(hi + i) = h;
  if (z >= 4) {
    ushort4 s;
    s.x = f2bf(v.x - bf2f(h.x));
    s.y = f2bf(v.y - bf2f(h.y));
    s.z = f2bf(v.z - bf2f(h.z));
    s.w = f2bf(v.w - bf2f(h.w));
    *(ushort4*)(lo + i) = s;
  }
}

// ---------------------------------------------------------------------------
// Staging + fragment read. Chunk-XOR swizzle on reads; LDS dest LINEAR,
// inverse swizzle on per-lane global source. 256 threads.
// ---------------------------------------------------------------------------
template <int NISS>
__device__ __forceinline__ void stage_tile(const u16* __restrict__ G, long ld,
                                           int row0, int k0, char* lds, int w,
                                           int l) {
#pragma unroll
  for (int i = 0; i < NISS; ++i) {
    const int off = i * 4096 + w * 1024 + l * 16;
    const int r = off >> 6;
    const int cp = (off >> 4) & 3;
    const int c = cp ^ ((r >> 1) & 3);
    __builtin_amdgcn_global_load_lds(
        (gptr_t)(G + (long)(row0 + r) * ld + k0 + c * 8),
        (sptr_t)(lds + i * 4096 + w * 1024), 16, 0, 0);
  }
}

__device__ __forceinline__ bf16x8 read_frag(const char* lds, int r, int ks) {
  const int cp = ks ^ ((r >> 1) & 3);
  return *(const bf16x8*)(lds + r * 64 + cp * 16);
}

__device__ __forceinline__ void core_plain(const u16* __restrict__ A, long lda,
                                           const u16* __restrict__ B, long ldb,
                                           int K, int bm, int bn, char* smem,
                                           f32x4 acc[4][4]) {
  const int tid = threadIdx.x, w = tid >> 6, l = tid & 63;
  const int wm = (w >> 1) * 64, wn = (w & 1) * 64;
  const int fr = l & 15, ks = l >> 4;
  char* As = smem;
  char* Bs = smem + 8192;
  for (int k0 = 0; k0 < K; k0 += 32) {
    stage_tile<2>(A, lda, bm, k0, As, w, l);
    stage_tile<2>(B, ldb, bn, k0, Bs, w, l);
    __syncthreads();
    bf16x8 af[4], bg[4];
#pragma unroll
    for (int i = 0; i < 4; ++i) {
      af[i] = read_frag(As, wm + i * 16 + fr, ks);
      bg[i] = read_frag(Bs, wn + i * 16 + fr, ks);
    }
#pragma unroll
    for (int mi = 0; mi < 4; ++mi)
#pragma unroll
      for (int ni = 0; ni < 4; ++ni)
        acc[mi][ni] = __builtin_amdgcn_mfma_f32_16x16x32_bf16(
            af[mi], bg[ni], acc[mi][ni], 0, 0, 0);
    __syncthreads();
  }
}

// split bf16 NT: hh + hl + lh (narrow: wave 64x64)
__device__ __forceinline__ void core_split(
    const u16* __restrict__ Ah, const u16* __restrict__ Al, long lda,
    const u16* __restrict__ Bh, const u16* __restrict__ Bl, long ldb, int K,
    int bm, int bn, char* smem, f32x4 acc[4][4]) {
  const int tid = threadIdx.x, w = tid >> 6, l = tid & 63;
  const int wm = (w >> 1) * 64, wn = (w & 1) * 64;
  const int fr = l & 15, ks = l >> 4;
  char* Ash = smem;
  char* Bsh = smem + 8192;
  char* Asl = smem + 16384;
  char* Bsl = smem + 24576;
  for (int k0 = 0; k0 < K; k0 += 32) {
    stage_tile<2>(Ah, lda, bm, k0, Ash, w, l);
    stage_tile<2>(Bh, ldb, bn, k0, Bsh, w, l);
    stage_tile<2>(Al, lda, bm, k0, Asl, w, l);
    stage_tile<2>(Bl, ldb, bn, k0, Bsl, w, l);
    __syncthreads();
    bf16x8 ah[4], bh[4];
#pragma unroll
    for (int i = 0; i < 4; ++i) {
      ah[i] = read_frag(Ash, wm + i * 16 + fr, ks);
      bh[i] = read_frag(Bsh, wn + i * 16 + fr, ks);
    }
#pragma unroll
    for (int mi = 0; mi < 4; ++mi)
#pragma unroll
      for (int ni = 0; ni < 4; ++ni)
        acc[mi][ni] = __builtin_amdgcn_mfma_f32_16x16x32_bf16(
            ah[mi], bh[ni], acc[mi][ni], 0, 0, 0);
    bf16x8 bl[4];
#pragma unroll
    for (int ni = 0; ni < 4; ++ni)
      bl[ni] = read_frag(Bsl, wn + ni * 16 + fr, ks);
#pragma unroll
    for (int mi = 0; mi < 4; ++mi)
#pragma unroll
      for (int ni = 0; ni < 4; ++ni)
        acc[mi][ni] = __builtin_amdgcn_mfma_f32_16x16x32_bf16(
            ah[mi], bl[ni], acc[mi][ni], 0, 0, 0);
    bf16x8 al[4];
#pragma unroll
    for (int mi = 0; mi < 4; ++mi)
      al[mi] = read_frag(Asl, wm + mi * 16 + fr, ks);
#pragma unroll
    for (int mi = 0; mi < 4; ++mi)
#pragma unroll
      for (int ni = 0; ni < 4; ++ni)
        acc[mi][ni] = __builtin_amdgcn_mfma_f32_16x16x32_bf16(
            al[mi], bh[ni], acc[mi][ni], 0, 0, 0);
    __syncthreads();
  }
}

// ---------------------------------------------------------------------------
// WIDE split core: block 128(M) x 256(N), wave 64x128 (2x2 waves).
// 1.33x less LDS traffic per FLOP than wave 64x64. Two-half B schedule keeps
// peak live regs ~192 (acc 128 + 4 frag arrays) -> no spill at (256,2).
// LDS: Ash 8K | Asl 8K | Bsh 16K | Bsl 16K = 48KB.
// ---------------------------------------------------------------------------
__device__ __forceinline__ void core_split_w(
    const u16* __restrict__ Ah, const u16* __restrict__ Al, long lda,
    const u16* __restrict__ Bh, const u16* __restrict__ Bl, long ldb, int K,
    int bm, int bn, char* smem, f32x4 acc[4][8]) {
  const int tid = threadIdx.x, w = tid >> 6, l = tid & 63;
  const int wm = (w >> 1) * 64, wn = (w & 1) * 128;
  const int fr = l & 15, ks = l >> 4;
  char* Ash = smem;
  char* Asl = smem + 8192;
  char* Bsh = smem + 16384;
  char* Bsl = smem + 32768;
  for (int k0 = 0; k0 < K; k0 += 32) {
    stage_tile<2>(Ah, lda, bm, k0, Ash, w, l);
    stage_tile<2>(Al, lda, bm, k0, Asl, w, l);
    stage_tile<4>(Bh, ldb, bn, k0, Bsh, w, l);
    stage_tile<4>(Bl, ldb, bn, k0, Bsl, w, l);
    __syncthreads();
    bf16x8 ah[4], al[4];
#pragma unroll
    for (int mi = 0; mi < 4; ++mi) {
      ah[mi] = read_frag(Ash, wm + mi * 16 + fr, ks);
      al[mi] = read_frag(Asl, wm + mi * 16 + fr, ks);
    }
#pragma unroll
    for (int hf = 0; hf < 2; ++hf) {
      const int base = wn + hf * 64;
      bf16x8 bh[4];
#pragma unroll
      for (int ni = 0; ni < 4; ++ni)
        bh[ni] = read_frag(Bsh, base + ni * 16 + fr, ks);
#pragma unroll
      for (int mi = 0; mi < 4; ++mi)
#pragma unroll
        for (int ni = 0; ni < 4; ++ni)
          acc[mi][hf * 4 + ni] = __builtin_amdgcn_mfma_f32_16x16x32_bf16(
              ah[mi], bh[ni], acc[mi][hf * 4 + ni], 0, 0, 0);
#pragma unroll
      for (int mi = 0; mi < 4; ++mi)
#pragma unroll
        for (int ni = 0; ni < 4; ++ni)
          acc[mi][hf * 4 + ni] = __builtin_amdgcn_mfma_f32_16x16x32_bf16(
              al[mi], bh[ni], acc[mi][hf * 4 + ni], 0, 0, 0);
      bf16x8 bl[4];
#pragma unroll
      for (int ni = 0; ni < 4; ++ni)
        bl[ni] = read_frag(Bsl, base + ni * 16 + fr, ks);
#pragma unroll
      for (int mi = 0; mi < 4; ++mi)
#pragma unroll
        for (int ni = 0; ni < 4; ++ni)
          acc[mi][hf * 4 + ni] = __builtin_amdgcn_mfma_f32_16x16x32_bf16(
              ah[mi], bl[ni], acc[mi][hf * 4 + ni], 0, 0, 0);
    }
    __syncthreads();
  }
}

// C/D coords: row = bm + wm + mi*16 + ks*4 + j, col = bn + wn + ni*16 + fr
#define EPI_PROLOG()                                       \
  const int tid = threadIdx.x, w = tid >> 6, l = tid & 63; \
  const int wm = (w >> 1) * 64, wn = (w & 1) * 64;         \
  const int fr = l & 15, ks = l >> 4;

#define EPI_PROLOG_W()                                     \
  const int tid = threadIdx.x, w = tid >> 6, l = tid & 63; \
  const int wm = (w >> 1) * 64, wn = (w & 1) * 128;        \
  const int fr = l & 15, ks = l >> 4;

// scan helper: map e over batches with c_b = mult*ceil(len_b/128)
__device__ __forceinline__ int scan_batches(const int* __restrict__ lens,
                                            int e, int mult, int* loc,
                                            int* rem) {
  for (int i = 0; i < NB; ++i) {
    const int c = mult * ((lens[i] + 127) >> 7);
    if (e < c) {
      *loc = e;
      return i;
    }
    e -= c;
  }
  *rem = e;
  return -1;
}

// ---------------------------------------------------------------------------
// Projections, compacted + XCD-chunked 1D grid (1536).
// ---------------------------------------------------------------------------
__global__ __launch_bounds__(256, 3) void k_proj_p(
    const u16* __restrict__ q_hi, const u16* __restrict__ k_hi,
    const u16* __restrict__ v_hi, const u16* __restrict__ Wq_h,
    const u16* __restrict__ Wk_h, const u16* __restrict__ Wv_h,
    const int* __restrict__ lens, u16* __restrict__ qp, u16* __restrict__ kp,
    u16* __restrict__ vp) {
  const int flat = xcd_chunk16(blockIdx.x);
  const u16 *A, *B;
  u16* C;
  int bm, bn;
  if (flat < 512) {
    A = q_hi;
    B = Wq_h;
    C = qp;
    bm = (flat >> 2) * 128;
    bn = (flat & 3) * 128;
  } else {
    int loc, rem;
    int b = scan_batches(lens, flat - 512, 4, &loc, &rem);
    if (b >= 0) {
      A = k_hi;
      B = Wk_h;
      C = kp;
    } else {
      b = scan_batches(lens, rem, 4, &loc, &rem);
      if (b < 0) return;
      A = v_hi;
      B = Wv_h;
      C = vp;
    }
    bm = b * 1024 + (loc >> 2) * 128;
    bn = (loc & 3) * 128;
  }
  __shared__ __align__(16) char smem[16384];
  f32x4 acc[4][4] = {};
  core_plain(A, DD, B, DD, DD, bm, bn, smem, acc);
  EPI_PROLOG()
#pragma unroll
  for (int mi = 0; mi < 4; ++mi) {
    const int R0 = bm + wm + mi * 16 + ks * 4;
#pragma unroll
    for (int ni = 0; ni < 4; ++ni) {
      const int col = bn + wn + ni * 16 + fr;
#pragma unroll
      for (int j = 0; j < 4; ++j)
        C[(long)(R0 + j) * DD + col] = f2bf(acc[mi][ni][j]);
    }
  }
}

// ---------------------------------------------------------------------------
// qt0/kt0 projections (split), SPLIT + TRANSPOSED output via LDS-transpose
// epilogue at (256,2) (r10 lesson: (256,3) spilled). grid (4, 128, 2).
// ---------------------------------------------------------------------------
__global__ __launch_bounds__(256, 2) void k_proj_t(
    const u16* __restrict__ q_hi, const u16* __restrict__ q_lo,
    const u16* __restrict__ k_hi, const u16* __restrict__ k_lo,
    const u16* __restrict__ Wqt_h, const u16* __restrict__ Wqt_l,
    const u16* __restrict__ Wkt_h, const u16* __restrict__ Wkt_l,
    u16* __restrict__ qT_h, u16* __restrict__ qT_l, u16* __restrict__ kT_h,
    u16* __restrict__ kT_l) {
  const int sel = blockIdx.z;
  const u16* Ah = sel ? k_hi : q_hi;
  const u16* Al = sel ? k_lo : q_lo;
  const u16* Bh = sel ? Wkt_h : Wqt_h;
  const u16* Bl = sel ? Wkt_l : Wqt_l;
  u16* Ch = sel ? kT_h : qT_h;
  u16* Cl = sel ? kT_l : qT_l;
  __shared__ __align__(16) char smem[32768];
  const int bm = blockIdx.y * 128, bn = blockIdx.x * 128;
  f32x4 acc[4][4] = {};
  core_split(Ah, Al, DD, Bh, Bl, DD, DD, bm, bn, smem, acc);
  EPI_PROLOG()
  u16* tb = (u16*)smem;  // 64*132 u16 = 16.5KB, reuse core smem (post-loop)
  const int b = bm >> 10, lr0 = bm & 1023;
  for (int part = 0; part < 2; ++part) {
    u16* OT = part ? Cl : Ch;
    for (int half = 0; half < 2; ++half) {
      __syncthreads();
      if ((wn >> 6) == half) {
#pragma unroll
        for (int mi = 0; mi < 4; ++mi) {
          const int rloc = wm + mi * 16 + ks * 4;
#pragma unroll
          for (int ni = 0; ni < 4; ++ni) {
            const int cloc = ni * 16 + fr;
#pragma unroll
            for (int j = 0; j < 4; ++j) {
              const float x = acc[mi][ni][j];
              const u16 h = f2bf(x);
              tb[cloc * 132 + rloc + j] = part ? f2bf(x - bf2f(h)) : h;
            }
          }
        }
      }
      __syncthreads();
      const int colg0 = bn + half * 64;
#pragma unroll
      for (int it = 0; it < 8; ++it) {
        const int i = (it * 256 + tid) * 4;
        const int cl = i >> 7, rl = i & 127;
        *(ushort4*)&OT[(long)b * LL * DD + (long)(colg0 + cl) * LL + lr0 +
                       rl] = *(ushort4*)&tb[cl * 132 + rl];
      }
    }
  }
}

// ---------------------------------------------------------------------------
// vp transpose only: [1024][512] -> [512][1024]; slabs >= len skipped.
// grid (8, 16, 16)
// ---------------------------------------------------------------------------
__global__ __launch_bounds__(256) void k_tr(const u16* __restrict__ vp,
                                            const int* __restrict__ lens,
                                            u16* __restrict__ vpT) {
  const int b = blockIdx.z;
  const int r0 = blockIdx.y * 64, c0 = blockIdx.x * 64;
  if (r0 >= lens[b]) return;
  const u16* X = vp + (long)b * LL * DD;
  u16* O = vpT + (long)b * LL * DD;
  __shared__ u16 t[64][68];
  const int tid = threadIdx.x;
#pragma unroll
  for (int i = 0; i < 16; ++i) {
    const int idx = tid + i * 256;
    t[idx >> 6][idx & 63] = X[(long)(r0 + (idx >> 6)) * DD + c0 + (idx & 63)];
  }
  __syncthreads();
#pragma unroll
  for (int i = 0; i < 16; ++i) {
    const int idx = tid + i * 256;
    const int rr = idx >> 6, cc = idx & 63;
    O[(long)(c0 + rr) * LL + r0 + cc] = t[cc][rr];
  }
}

// ---------------------------------------------------------------------------
// distance matmuls (split, WIDE core 128x256). grid 512, XCD-chunked:
//   [0,256): qt tiles (b = flat>>4, 8bm x 2bn); then kt kept tiles (mult=2)
// ---------------------------------------------------------------------------
__global__ __launch_bounds__(256, 2) void k_dist_g(
    const u16* __restrict__ dist_h, const u16* __restrict__ dist_l,
    const u16* __restrict__ qT_h, const u16* __restrict__ qT_l,
    const u16* __restrict__ kT_h, const u16* __restrict__ kT_l,
    const int* __restrict__ lens, u16* __restrict__ qt_h,
    u16* __restrict__ qt_l, u16* __restrict__ kt_h, u16* __restrict__ kt_l) {
  const int flat = xcd_chunk16(blockIdx.x);
  int b, sel, bm, bn;
  if (flat < 256) {
    sel = 0;
    b = flat >> 4;
    const int r = flat & 15;  // 8 bm x 2 bn, bn inner (dist-panel reuse)
    bm = (r >> 1) * 128;
    bn = (r & 1) * 256;
  } else {
    int loc, rem;
    b = scan_batches(lens, flat - 256, 2, &loc, &rem);
    if (b < 0) return;
    sel = 1;
    bm = (loc >> 1) * 128;
    bn = (loc & 1) * 256;
  }
  const u16* Ah = dist_h + (long)b * LL * LL;
  const u16* Al = dist_l + (long)b * LL * LL;
  const u16* Bh = (sel ? kT_h : qT_h) + (long)b * LL * DD;
  const u16* Bl = (sel ? kT_l : qT_l) + (long)b * LL * DD;
  u16* Oh = (sel ? kt_h : qt_h) + (long)b * LL * DD;
  u16* Ol = (sel ? kt_l : qt_l) + (long)b * LL * DD;
  __shared__ __align__(16) char smem[49152];
  f32x4 acc[4][8] = {};
  core_split_w(Ah, Al, LL, Bh, Bl, LL, LL, bm, bn, smem, acc);
  EPI_PROLOG_W()
#pragma unroll
  for (int mi = 0; mi < 4; ++mi) {
    const int R0 = bm + wm + mi * 16 + ks * 4;
#pragma unroll
    for (int ni = 0; ni < 8; ++ni) {
      const int col = bn + wn + ni * 16 + fr;
#pragma unroll
      for (int j = 0; j < 4; ++j) {
        const long idx = (long)(R0 + j) * DD + col;
        const float x = acc[mi][ni][j];
        const u16 h = f2bf(x);
        Oh[idx] = h;
        Ol[idx] = f2bf(x - bf2f(h));
      }
    }
  }
}

// ---------------------------------------------------------------------------
// scores, compacted + XCD-chunked grid (1024): compute tiles first with
// stripe-4 within batch; remaining blocks zero-fill masked tiles.
// Merged K-loop (6 LDS tiles, 48KB static).
// ---------------------------------------------------------------------------
__global__ __launch_bounds__(256, 3) void k_score(
    const u16* __restrict__ qp, const u16* __restrict__ kp,
    const u16* __restrict__ qt_h, const u16* __restrict__ qt_l,
    const u16* __restrict__ kt_h, const u16* __restrict__ kt_l,
    const int* __restrict__ lens, float* __restrict__ attnF,
    u16* __restrict__ attnB) {
  const int tid = threadIdx.x;
  int loc, rem;
  int b = scan_batches(lens, xcd_chunk16(blockIdx.x), 8, &loc, &rem);
  int bm, bn;
  if (b < 0) {  // masked-tile region: zero-fill
    for (int i = 0; i < NB; ++i) {
      const int nbn = (lens[i] + 127) >> 7;
      const int c = (8 - nbn) << 3;
      if (rem < c) {
        b = i;
        const int wdt = 8 - nbn;
        bm = (rem / wdt) * 128;
        bn = (nbn + rem % wdt) * 128;
        break;
      }
      rem -= c;
    }
    if (b < 0) return;
    const long baseF = (long)b * LL * LL;
    const float4 zf = make_float4(0.f, 0.f, 0.f, 0.f);
    const ushort4 zh = {0, 0, 0, 0};
    for (int i = tid; i < 4096; i += 256) {
      const int row = i >> 5, c = (i & 31) << 2;
      const long idx = baseF + (long)(bm + row) * LL + bn + c;
      *(float4*)&attnF[idx] = zf;
      *(ushort4*)&attnB[idx] = zh;
    }
    return;
  }
  const int nbn = (lens[b] + 127) >> 7;
  {  // stripe-4: bm fastest in groups of 4
    const int S = nbn << 2;
    const int s = loc / S, inner = loc - s * S;
    bm = (s * 4 + (inner & 3)) * 128;
    bn = (inner >> 2) * 128;
  }
  const int len = lens[b];
  const long baseF = (long)b * LL * LL;
  const long od = (long)b * LL * DD;
  const u16* Ah = qt_h + od;
  const u16* Al = qt_l + od;
  const u16* Bh = kt_h + od;
  const u16* Bl = kt_l + od;
  const u16* Ap = qp + od;
  const u16* Bp = kp + od;
  __shared__ __align__(16) char smem[49152];
  char* Ash = smem;
  char* Bsh = smem + 8192;
  char* Asl = smem + 16384;
  char* Bsl = smem + 24576;
  char* Aps = smem + 32768;
  char* Bps = smem + 40960;
  const int w = tid >> 6, l = tid & 63;
  const int wm = (w >> 1) * 64, wn = (w & 1) * 64;
  const int fr = l & 15, ks = l >> 4;
  f32x4 acc[4][4] = {};
  for (int k0 = 0; k0 < DD; k0 += 32) {
    stage_tile<2>(Ah, DD, bm, k0, Ash, w, l);
    stage_tile<2>(Bh, DD, bn, k0, Bsh, w, l);
    stage_tile<2>(Al, DD, bm, k0, Asl, w, l);
    stage_tile<2>(Bl, DD, bn, k0, Bsl, w, l);
    stage_tile<2>(Ap, DD, bm, k0, Aps, w, l);
    stage_tile<2>(Bp, DD, bn, k0, Bps, w, l);
    __syncthreads();
    bf16x8 ah[4], bh[4];
#pragma unroll
    for (int i = 0; i < 4; ++i) {
      ah[i] = read_frag(Ash, wm + i * 16 + fr, ks);
      bh[i] = read_frag(Bsh, wn + i * 16 + fr, ks);
    }
#pragma unroll
    for (int mi = 0; mi < 4; ++mi)
#pragma unroll
      for (int ni = 0; ni < 4; ++ni)
        acc[mi][ni] = __builtin_amdgcn_mfma_f32_16x16x32_bf16(
            ah[mi], bh[ni], acc[mi][ni], 0, 0, 0);
    bf16x8 bl[4];
#pragma unroll
    for (int ni = 0; ni < 4; ++ni)
      bl[ni] = read_frag(Bsl, wn + ni * 16 + fr, ks);
#pragma unroll
    for (int mi = 0; mi < 4; ++mi)
#pragma unroll
      for (int ni = 0; ni < 4; ++ni)
        acc[mi][ni] = __builtin_amdgcn_mfma_f32_16x16x32_bf16(
            ah[mi], bl[ni], acc[mi][ni], 0, 0, 0);
    bf16x8 al[4];
#pragma unroll
    for (int mi = 0; mi < 4; ++mi)
      al[mi] = read_frag(Asl, wm + mi * 16 + fr, ks);
#pragma unroll
    for (int mi = 0; mi < 4; ++mi)
#pragma unroll
      for (int ni = 0; ni < 4; ++ni)
        acc[mi][ni] = __builtin_amdgcn_mfma_f32_16x16x32_bf16(
            al[mi], bh[ni], acc[mi][ni], 0, 0, 0);
    bf16x8 ap[4], bp[4];
#pragma unroll
    for (int i = 0; i < 4; ++i) {
      ap[i] = read_frag(Aps, wm + i * 16 + fr, ks);
      bp[i] = read_frag(Bps, wn + i * 16 + fr, ks);
    }
#pragma unroll
    for (int mi = 0; mi < 4; ++mi)
#pragma unroll
      for (int ni = 0; ni < 4; ++ni)
        acc[mi][ni] = __builtin_amdgcn_mfma_f32_16x16x32_bf16(
            ap[mi], bp[ni], acc[mi][ni], 0, 0, 0);
    __syncthreads();
  }
  const float invt = 0.04419417382415922f;  // 1/sqrt(512)
#pragma unroll
  for (int mi = 0; mi < 4; ++mi) {
    const int R0 = bm + wm + mi * 16 + ks * 4;
#pragma unroll
    for (int ni = 0; ni < 4; ++ni) {
      const int col = bn + wn + ni * 16 + fr;
      const float m = (col < len) ? 1.0f : 0.0f;
#pragma unroll
      for (int j = 0; j < 4; ++j) {
        const float s = tanhf(acc[mi][ni][j] * invt * m) * m;
        const long idx = baseF + (long)(R0 + j) * LL + col;
        attnF[idx] = s;
        attnB[idx] = f2bf(s);
      }
    }
  }
}

// ---------------------------------------------------------------------------
// PV: out0 = attn * vp (via vpT), K truncated to ceil(len/32)*32.
// XCD-chunked grid (512), batch-contiguous, bn fastest.
// ---------------------------------------------------------------------------
__global__ __launch_bounds__(256, 3) void k_pv(const u16* __restrict__ attnB,
                                               const u16* __restrict__ vpT,
                                               const int* __restrict__ lens,
                                               u16* __restrict__ out0) {
  const int flat = xcd_chunk16(blockIdx.x);
  const int b = flat >> 5;
  const int r = flat & 31;
  const int bm = (r >> 2) * 128, bn = (r & 3) * 128;
  const int Kt = ((lens[b] + 31) >> 5) << 5;
  __shared__ __align__(16) char smem[16384];
  f32x4 acc[4][4] = {};
  core_plain(attnB + (long)b * LL * LL, LL, vpT + (long)b * LL * DD, LL, Kt,
             bm, bn, smem, acc);
  u16* C = out0 + (long)b * LL * DD;
  EPI_PROLOG()
#pragma unroll
  for (int mi = 0; mi < 4; ++mi) {
    const int R0 = bm + wm + mi * 16 + ks * 4;
#pragma unroll
    for (int ni = 0; ni < 4; ++ni) {
      const int col = bn + wn + ni * 16 + fr;
#pragma unroll
      for (int j = 0; j < 4; ++j)
        C[(long)(R0 + j) * DD + col] = f2bf(acc[mi][ni][j]);
    }
  }
}

// ---------------------------------------------------------------------------
// Fused FC + residual + LayerNorm. 64 rows x full 512 cols. grid (256)
// ---------------------------------------------------------------------------
__global__ __launch_bounds__(256, 2) void k_fcln(
    const u16* __restrict__ out0, const u16* __restrict__ Wfc_h,
    const float* __restrict__ q, const float* __restrict__ gamma,
    const float* __restrict__ beta, float* __restrict__ outO) {
  __shared__ __align__(16) char smem[36864];  // As 4KB + Bs 32KB
  __shared__ float red[2][64][5];
  const int tid = threadIdx.x, w = tid >> 6, l = tid & 63;
  const int wn = w * 128;
  const int fr = l & 15, ks = l >> 4;
  const int bm = blockIdx.x * 64;
  char* As = smem;
  char* Bs = smem + 4096;
  f32x4 acc[4][8] = {};
  for (int k0 = 0; k0 < DD; k0 += 32) {
    stage_tile<1>(out0, DD, bm, k0, As, w, l);
    stage_tile<8>(Wfc_h, DD, 0, k0, Bs, w, l);
    __syncthreads();
    bf16x8 af[4], bg[8];
#pragma unroll
    for (int mi = 0; mi < 4; ++mi) af[mi] = read_frag(As, mi * 16 + fr, ks);
#pragma unroll
    for (int ni = 0; ni < 8; ++ni)
      bg[ni] = read_frag(Bs, wn + ni * 16 + fr, ks);
#pragma unroll
    for (int mi = 0; mi < 4; ++mi)
#pragma unroll
      for (int ni = 0; ni < 8; ++ni)
        acc[mi][ni] = __builtin_amdgcn_mfma_f32_16x16x32_bf16(
            af[mi], bg[ni], acc[mi][ni], 0, 0, 0);
    __syncthreads();
  }
  float p1[4][4], p2[4][4];
#pragma unroll
  for (int mi = 0; mi < 4; ++mi)
#pragma unroll
    for (int j = 0; j < 4; ++j) {
      p1[mi][j] = 0.0f;
      p2[mi][j] = 0.0f;
    }
#pragma unroll
  for (int mi = 0; mi < 4; ++mi) {
    const int r = mi * 16 + ks * 4;
#pragma unroll
    for (int ni = 0; ni < 8; ++ni) {
      const int col = wn + ni * 16 + fr;
#pragma unroll
      for (int j = 0; j < 4; ++j) {
        const float val = acc[mi][ni][j] + q[(long)(bm + r + j) * DD + col];
        acc[mi][ni][j] = val;
        p1[mi][j] += val;
        p2[mi][j] += val * val;
      }
    }
  }
#pragma unroll
  for (int off = 1; off < 16; off <<= 1) {
#pragma unroll
    for (int mi = 0; mi < 4; ++mi)
#pragma unroll
      for (int j = 0; j < 4; ++j) {
        p1[mi][j] += __shfl_xor(p1[mi][j], off);
        p2[mi][j] += __shfl_xor(p2[mi][j], off);
      }
  }
  if (fr == 0) {
#pragma unroll
    for (int mi = 0; mi < 4; ++mi)
#pragma unroll
      for (int j = 0; j < 4; ++j) {
        red[0][mi * 16 + ks * 4 + j][w] = p1[mi][j];
        red[1][mi * 16 + ks * 4 + j][w] = p2[mi][j];
      }
  }
  __syncthreads();
#pragma unroll
  for (int mi = 0; mi < 4; ++mi) {
#pragma unroll
    for (int j = 0; j < 4; ++j) {
      const int r = mi * 16 + ks * 4 + j;
      const float s1 =
          red[0][r][0] + red[0][r][1] + red[0][r][2] + red[0][r][3];
      const float s2 =
          red[1][r][0] + red[1][r][1] + red[1][r][2] + red[1][r][3];
      const float mu = s1 * (1.0f / DD);
      const float rs = rsqrtf(s2 * (1.0f / DD) - mu * mu + 1e-6f);
#pragma unroll
      for (int ni = 0; ni < 8; ++ni) {
        const int col = wn + ni * 16 + fr;
        outO[(long)(bm + r) * DD + col] =
            (acc[mi][ni][j] - mu) * rs * gamma[col] + beta[col];
      }
    }
  }
}

// ---------------------------------------------------------------------------
extern "C" void kernel_launch(void* const* d_in, const int* in_sizes, int n_in,
                              void* d_out, int out_size, void* d_ws,
                              size_t ws_size, hipStream_t stream) {
  const float* q = (const float*)d_in[0];
  const float* k = (const float*)d_in[1];
  const float* v = (const float*)d_in[2];
  const int* lens = (const int*)d_in[3];
  const float* dist = (const float*)d_in[4];
  const float* Wq = (const float*)d_in[5];
  const float* Wk = (const float*)d_in[6];
  const float* Wv = (const float*)d_in[7];
  const float* Wqt = (const float*)d_in[8];
  const float* Wkt = (const float*)d_in[9];
  const float* Wfc = (const float*)d_in[10];
  const float* gamma = (const float*)d_in[11];
  const float* beta = (const float*)d_in[12];

  char* W = (char*)d_ws;
  const size_t SB = 16777216;  // bytes of one bf16 [16384][512] buffer
  u16* q_hi = (u16*)(W + 0 * SB);    // reused later as qt_h
  u16* q_lo = (u16*)(W + 1 * SB);    // reused later as qt_l
  u16* k_hi = (u16*)(W + 2 * SB);    // reused later as kt_h
  u16* k_lo = (u16*)(W + 3 * SB);    // reused later as kt_l
  u16* v_hi = (u16*)(W + 4 * SB);    // reused later as vpT
  u16* dist_h = (u16*)(W + 5 * SB);  // 2SB; reused later as attnB
  u16* dist_l = (u16*)(W + 7 * SB);  // 2SB
  u16* qp_bf = (u16*)(W + 9 * SB);   // reused later as out0
  u16* kp_bf = (u16*)(W + 10 * SB);
  u16* vp_bf = (u16*)(W + 11 * SB);
  u16* qT_h = (u16*)(W + 16 * SB);   // written transposed by k_proj_t
  u16* qT_l = (u16*)(W + 17 * SB);
  u16* kT_h = (u16*)(W + 18 * SB);
  u16* kT_l = (u16*)(W + 19 * SB);
  char* WB = W + 20 * SB;
  const size_t WS = 524288;
  u16* Wq_h = (u16*)(WB + 0 * WS);
  u16* Wk_h = (u16*)(WB + 1 * WS);
  u16* Wv_h = (u16*)(WB + 2 * WS);
  u16* Wfc_h = (u16*)(WB + 3 * WS);
  u16* Wqt_h = (u16*)(WB + 4 * WS);
  u16* Wqt_l = (u16*)(WB + 5 * WS);
  u16* Wkt_h = (u16*)(WB + 6 * WS);
  u16* Wkt_l = (u16*)(WB + 7 * WS);
  // aliases (lifetimes disjoint, stream-ordered)
  u16* qt_h = q_hi;
  u16* qt_l = q_lo;
  u16* kt_h = k_hi;
  u16* kt_l = k_lo;
  u16* vpT = v_hi;
  u16* attnB = dist_h;
  u16* out0 = qp_bf;

  float* outO = (float*)d_out;
  float* attnF = outO + NLD;

  dim3 blk(256);
  k_split3<<<dim3(1024, 1, 3), blk, 0, stream>>>(q, k, v, q_hi, q_lo, k_hi,
                                                 k_lo, v_hi);
  k_splitd<<<4096, blk, 0, stream>>>(dist, dist_h, dist_l);
  k_splitw<<<dim3(256, 1, 6), blk, 0, stream>>>(Wq, Wk, Wv, Wfc, Wqt, Wkt,
                                                Wq_h, Wk_h, Wv_h, Wfc_h,
                                                Wqt_h, Wqt_l, Wkt_h, Wkt_l);

  k_proj_p<<<1536, blk, 0, stream>>>(q_hi, k_hi, v_hi, Wq_h, Wk_h, Wv_h, lens,
                                     qp_bf, kp_bf, vp_bf);
  k_proj_t<<<dim3(4, 128, 2), blk, 0, stream>>>(q_hi, q_lo, k_hi, k_lo, Wqt_h,
                                                Wqt_l, Wkt_h, Wkt_l, qT_h,
                                                qT_l, kT_h, kT_l);
  k_tr<<<dim3(8, 16, 16), blk, 0, stream>>>(vp_bf, lens, vpT);
  k_dist_g<<<512, blk, 0, stream>>>(dist_h, dist_l, qT_h, qT_l, kT_h, kT_l,
                                    lens, qt_h, qt_l, kt_h, kt_l);
  k_score<<<1024, blk, 0, stream>>>(qp_bf, kp_bf, qt_h, qt_l, kt_h, kt_l,
                                    lens, attnF, attnB);
  k_pv<<<512, blk, 0, stream>>>(attnB, vpT, lens, out0);
  k_fcln<<<256, blk, 0, stream>>>(out0, Wfc_h, q, gamma, beta, outO);
}

// Round 13
// 390.978 us; speedup vs baseline: 1.0339x; 1.0339x over previous
//
#include <hip/hip_runtime.h>
#include <math.h>

#define LL 1024
#define DD 512
#define NB 16

typedef __attribute__((ext_vector_type(8))) short bf16x8;
typedef __attribute__((ext_vector_type(4))) float f32x4;
typedef unsigned short u16;
typedef unsigned int u32;
typedef const __attribute__((address_space(1))) void* gptr_t;
typedef __attribute__((address_space(3))) void* sptr_t;

static const long NLD = (long)NB * LL * DD;  // 8,388,608
static const long NLL = (long)NB * LL * LL;  // 16,777,216

__device__ __forceinline__ u16 f2bf(float x) {
  u32 u = __float_as_uint(x);
  u += 0x7fffu + ((u >> 16) & 1u);
  return (u16)(u >> 16);
}
__device__ __forceinline__ float bf2f(u16 h) {
  return __uint_as_float((u32)h << 16);
}

// XCD-chunked bijective remap (grids multiple of 128): 16-chunk per XCD.
__device__ __forceinline__ int xcd_chunk16(int flat) {
  const int j = flat >> 3;
  return ((j >> 4) << 7) + ((flat & 7) << 4) + (j & 15);
}

// ---------------------------------------------------------------------------
// q/k/v -> bf16 hi(+lo). z: 0=q(split) 1=k(split) 2=v(plain)
// ---------------------------------------------------------------------------
__global__ __launch_bounds__(256) void k_split3(
    const float* __restrict__ q, const float* __restrict__ k,
    const float* __restrict__ v, u16* __restrict__ qh, u16* __restrict__ ql,
    u16* __restrict__ kh, u16* __restrict__ kl, u16* __restrict__ vh) {
  const int z = blockIdx.z;
  const float* x = (z == 0) ? q : (z == 1) ? k : v;
  u16* hi = (z == 0) ? qh : (z == 1) ? kh : vh;
  u16* lo = (z == 0) ? ql : kl;
  const long stride = (long)gridDim.x * 1024;
  for (long i = ((long)blockIdx.x * 256 + threadIdx.x) * 4; i < NLD;
       i += stride) {
    const float4 vv = *(const float4*)(x + i);
    ushort4 h;
    h.x = f2bf(vv.x);
    h.y = f2bf(vv.y);
    h.z = f2bf(vv.z);
    h.w = f2bf(vv.w);
    *(ushort4*)(hi + i) = h;
    if (z < 2) {
      ushort4 s;
      s.x = f2bf(vv.x - bf2f(h.x));
      s.y = f2bf(vv.y - bf2f(h.y));
      s.z = f2bf(vv.z - bf2f(h.z));
      s.w = f2bf(vv.w - bf2f(h.w));
      *(ushort4*)(lo + i) = s;
    }
  }
}

// dist -> split bf16
__global__ __launch_bounds__(256) void k_splitd(const float* __restrict__ x,
                                                u16* __restrict__ hi,
                                                u16* __restrict__ lo) {
  const long stride = (long)gridDim.x * 1024;
  for (long i = ((long)blockIdx.x * 256 + threadIdx.x) * 4; i < NLL;
       i += stride) {
    const float4 v = *(const float4*)(x + i);
    ushort4 h, s;
    h.x = f2bf(v.x);
    h.y = f2bf(v.y);
    h.z = f2bf(v.z);
    h.w = f2bf(v.w);
    s.x = f2bf(v.x - bf2f(h.x));
    s.y = f2bf(v.y - bf2f(h.y));
    s.z = f2bf(v.z - bf2f(h.z));
    s.w = f2bf(v.w - bf2f(h.w));
    *(ushort4*)(hi + i) = h;
    *(ushort4*)(lo + i) = s;
  }
}

// all 6 weights. z: 0..3 plain (Wq,Wk,Wv,Wfc), 4..5 split (Wqt,Wkt)
__global__ __launch_bounds__(256) void k_splitw(
    const float* __restrict__ Wq, const float* __restrict__ Wk,
    const float* __restrict__ Wv, const float* __restrict__ Wfc,
    const float* __restrict__ Wqt, const float* __restrict__ Wkt,
    u16* __restrict__ Wq_h, u16* __restrict__ Wk_h, u16* __restrict__ Wv_h,
    u16* __restrict__ Wfc_h, u16* __restrict__ Wqt_h,
    u16* __restrict__ Wqt_l, u16* __restrict__ Wkt_h,
    u16* __restrict__ Wkt_l) {
  const int z = blockIdx.z;
  const float* x;
  u16 *hi, *lo = nullptr;
  switch (z) {
    case 0: x = Wq; hi = Wq_h; break;
    case 1: x = Wk; hi = Wk_h; break;
    case 2: x = Wv; hi = Wv_h; break;
    case 3: x = Wfc; hi = Wfc_h; break;
    case 4: x = Wqt; hi = Wqt_h; lo = Wqt_l; break;
    default: x = Wkt; hi = Wkt_h; lo = Wkt_l; break;
  }
  const long i = ((long)blockIdx.x * 256 + threadIdx.x) * 4;
  const float4 v = *(const float4*)(x + i);
  ushort4 h;
  h.x = f2bf(v.x);
  h.y = f2bf(v.y);
  h.z = f2bf(v.z);
  h.w = f2bf(v.w);
  *(ushort4*)(hi + i) = h;
  if (z >= 4) {
    ushort4 s;
    s.x = f2bf(v.x - bf2f(h.x));
    s.y = f2bf(v.y - bf2f(h.y));
    s.z = f2bf(v.z - bf2f(h.z));
    s.w = f2bf(v.w - bf2f(h.w));
    *(ushort4*)(lo + i) = s;
  }
}

// ---------------------------------------------------------------------------
// GEMM cores (round-8 proven): 256 threads = 4 waves (2x2), tile 128x128,
// BK=32, single-buffered LDS, 2 barriers/K-step. Chunk-XOR swizzle on reads;
// staging keeps LDS dest LINEAR, inverse swizzle on global source.
// ---------------------------------------------------------------------------
template <int NISS>
__device__ __forceinline__ void stage_tile(const u16* __restrict__ G, long ld,
                                           int row0, int k0, char* lds, int w,
                                           int l) {
#pragma unroll
  for (int i = 0; i < NISS; ++i) {
    const int off = i * 4096 + w * 1024 + l * 16;
    const int r = off >> 6;
    const int cp = (off >> 4) & 3;
    const int c = cp ^ ((r >> 1) & 3);
    __builtin_amdgcn_global_load_lds(
        (gptr_t)(G + (long)(row0 + r) * ld + k0 + c * 8),
        (sptr_t)(lds + i * 4096 + w * 1024), 16, 0, 0);
  }
}

__device__ __forceinline__ bf16x8 read_frag(const char* lds, int r, int ks) {
  const int cp = ks ^ ((r >> 1) & 3);
  return *(const bf16x8*)(lds + r * 64 + cp * 16);
}

__device__ __forceinline__ void core_plain(const u16* __restrict__ A, long lda,
                                           const u16* __restrict__ B, long ldb,
                                           int K, int bm, int bn, char* smem,
                                           f32x4 acc[4][4]) {
  const int tid = threadIdx.x, w = tid >> 6, l = tid & 63;
  const int wm = (w >> 1) * 64, wn = (w & 1) * 64;
  const int fr = l & 15, ks = l >> 4;
  char* As = smem;
  char* Bs = smem + 8192;
  for (int k0 = 0; k0 < K; k0 += 32) {
    stage_tile<2>(A, lda, bm, k0, As, w, l);
    stage_tile<2>(B, ldb, bn, k0, Bs, w, l);
    __syncthreads();
    bf16x8 af[4], bg[4];
#pragma unroll
    for (int i = 0; i < 4; ++i) {
      af[i] = read_frag(As, wm + i * 16 + fr, ks);
      bg[i] = read_frag(Bs, wn + i * 16 + fr, ks);
    }
#pragma unroll
    for (int mi = 0; mi < 4; ++mi)
#pragma unroll
      for (int ni = 0; ni < 4; ++ni)
        acc[mi][ni] = __builtin_amdgcn_mfma_f32_16x16x32_bf16(
            af[mi], bg[ni], acc[mi][ni], 0, 0, 0);
    __syncthreads();
  }
}

// split bf16 NT: hh + hl + lh
__device__ __forceinline__ void core_split(
    const u16* __restrict__ Ah, const u16* __restrict__ Al, long lda,
    const u16* __restrict__ Bh, const u16* __restrict__ Bl, long ldb, int K,
    int bm, int bn, char* smem, f32x4 acc[4][4]) {
  const int tid = threadIdx.x, w = tid >> 6, l = tid & 63;
  const int wm = (w >> 1) * 64, wn = (w & 1) * 64;
  const int fr = l & 15, ks = l >> 4;
  char* Ash = smem;
  char* Bsh = smem + 8192;
  char* Asl = smem + 16384;
  char* Bsl = smem + 24576;
  for (int k0 = 0; k0 < K; k0 += 32) {
    stage_tile<2>(Ah, lda, bm, k0, Ash, w, l);
    stage_tile<2>(Bh, ldb, bn, k0, Bsh, w, l);
    stage_tile<2>(Al, lda, bm, k0, Asl, w, l);
    stage_tile<2>(Bl, ldb, bn, k0, Bsl, w, l);
    __syncthreads();
    bf16x8 ah[4], bh[4];
#pragma unroll
    for (int i = 0; i < 4; ++i) {
      ah[i] = read_frag(Ash, wm + i * 16 + fr, ks);
      bh[i] = read_frag(Bsh, wn + i * 16 + fr, ks);
    }
#pragma unroll
    for (int mi = 0; mi < 4; ++mi)
#pragma unroll
      for (int ni = 0; ni < 4; ++ni)
        acc[mi][ni] = __builtin_amdgcn_mfma_f32_16x16x32_bf16(
            ah[mi], bh[ni], acc[mi][ni], 0, 0, 0);
    bf16x8 bl[4];
#pragma unroll
    for (int ni = 0; ni < 4; ++ni)
      bl[ni] = read_frag(Bsl, wn + ni * 16 + fr, ks);
#pragma unroll
    for (int mi = 0; mi < 4; ++mi)
#pragma unroll
      for (int ni = 0; ni < 4; ++ni)
        acc[mi][ni] = __builtin_amdgcn_mfma_f32_16x16x32_bf16(
            ah[mi], bl[ni], acc[mi][ni], 0, 0, 0);
    bf16x8 al[4];
#pragma unroll
    for (int mi = 0; mi < 4; ++mi)
      al[mi] = read_frag(Asl, wm + mi * 16 + fr, ks);
#pragma unroll
    for (int mi = 0; mi < 4; ++mi)
#pragma unroll
      for (int ni = 0; ni < 4; ++ni)
        acc[mi][ni] = __builtin_amdgcn_mfma_f32_16x16x32_bf16(
            al[mi], bh[ni], acc[mi][ni], 0, 0, 0);
    __syncthreads();
  }
}

// C/D coords: row = bm + wm + mi*16 + ks*4 + j, col = bn + wn + ni*16 + fr
#define EPI_PROLOG()                                       \
  const int tid = threadIdx.x, w = tid >> 6, l = tid & 63; \
  const int wm = (w >> 1) * 64, wn = (w & 1) * 64;         \
  const int fr = l & 15, ks = l >> 4;

// scan helper: map e over batches with c_b = mult*ceil(len_b/128)
__device__ __forceinline__ int scan_batches(const int* __restrict__ lens,
                                            int e, int mult, int* loc,
                                            int* rem) {
  for (int i = 0; i < NB; ++i) {
    const int c = mult * ((lens[i] + 127) >> 7);
    if (e < c) {
      *loc = e;
      return i;
    }
    e -= c;
  }
  *rem = e;
  return -1;
}

// ---------------------------------------------------------------------------
// Projections, compacted + XCD-chunked 1D grid (1536).
// ---------------------------------------------------------------------------
__global__ __launch_bounds__(256, 3) void k_proj_p(
    const u16* __restrict__ q_hi, const u16* __restrict__ k_hi,
    const u16* __restrict__ v_hi, const u16* __restrict__ Wq_h,
    const u16* __restrict__ Wk_h, const u16* __restrict__ Wv_h,
    const int* __restrict__ lens, u16* __restrict__ qp, u16* __restrict__ kp,
    u16* __restrict__ vp) {
  const int flat = xcd_chunk16(blockIdx.x);
  const u16 *A, *B;
  u16* C;
  int bm, bn;
  if (flat < 512) {
    A = q_hi;
    B = Wq_h;
    C = qp;
    bm = (flat >> 2) * 128;
    bn = (flat & 3) * 128;
  } else {
    int loc, rem;
    int b = scan_batches(lens, flat - 512, 4, &loc, &rem);
    if (b >= 0) {
      A = k_hi;
      B = Wk_h;
      C = kp;
    } else {
      b = scan_batches(lens, rem, 4, &loc, &rem);
      if (b < 0) return;
      A = v_hi;
      B = Wv_h;
      C = vp;
    }
    bm = b * 1024 + (loc >> 2) * 128;
    bn = (loc & 3) * 128;
  }
  __shared__ __align__(16) char smem[16384];
  f32x4 acc[4][4] = {};
  core_plain(A, DD, B, DD, DD, bm, bn, smem, acc);
  EPI_PROLOG()
#pragma unroll
  for (int mi = 0; mi < 4; ++mi) {
    const int R0 = bm + wm + mi * 16 + ks * 4;
#pragma unroll
    for (int ni = 0; ni < 4; ++ni) {
      const int col = bn + wn + ni * 16 + fr;
#pragma unroll
      for (int j = 0; j < 4; ++j)
        C[(long)(R0 + j) * DD + col] = f2bf(acc[mi][ni][j]);
    }
  }
}

// ---------------------------------------------------------------------------
// qt0/kt0 projections (split), written SPLIT + TRANSPOSED directly to
// qT/kT [b][512][1024] via LDS-transpose epilogue. (256,2): no spill (r10
// lesson: (256,3) + acc-alive-across-epilogue spilled the core loop).
// grid (4, 128, 2).
// ---------------------------------------------------------------------------
__global__ __launch_bounds__(256, 2) void k_proj_t(
    const u16* __restrict__ q_hi, const u16* __restrict__ q_lo,
    const u16* __restrict__ k_hi, const u16* __restrict__ k_lo,
    const u16* __restrict__ Wqt_h, const u16* __restrict__ Wqt_l,
    const u16* __restrict__ Wkt_h, const u16* __restrict__ Wkt_l,
    u16* __restrict__ qT_h, u16* __restrict__ qT_l, u16* __restrict__ kT_h,
    u16* __restrict__ kT_l) {
  const int sel = blockIdx.z;
  const u16* Ah = sel ? k_hi : q_hi;
  const u16* Al = sel ? k_lo : q_lo;
  const u16* Bh = sel ? Wkt_h : Wqt_h;
  const u16* Bl = sel ? Wkt_l : Wqt_l;
  u16* Ch = sel ? kT_h : qT_h;
  u16* Cl = sel ? kT_l : qT_l;
  __shared__ __align__(16) char smem[32768];
  const int bm = blockIdx.y * 128, bn = blockIdx.x * 128;
  f32x4 acc[4][4] = {};
  core_split(Ah, Al, DD, Bh, Bl, DD, DD, bm, bn, smem, acc);
  EPI_PROLOG()
  u16* tb = (u16*)smem;  // 64*132 u16 = 16.5KB, reuse core smem (post-loop)
  const int b = bm >> 10, lr0 = bm & 1023;
  for (int part = 0; part < 2; ++part) {
    u16* OT = part ? Cl : Ch;
    for (int half = 0; half < 2; ++half) {
      __syncthreads();
      if ((wn >> 6) == half) {
#pragma unroll
        for (int mi = 0; mi < 4; ++mi) {
          const int rloc = wm + mi * 16 + ks * 4;
#pragma unroll
          for (int ni = 0; ni < 4; ++ni) {
            const int cloc = ni * 16 + fr;
#pragma unroll
            for (int j = 0; j < 4; ++j) {
              const float x = acc[mi][ni][j];
              const u16 h = f2bf(x);
              tb[cloc * 132 + rloc + j] = part ? f2bf(x - bf2f(h)) : h;
            }
          }
        }
      }
      __syncthreads();
      const int colg0 = bn + half * 64;
#pragma unroll
      for (int it = 0; it < 8; ++it) {
        const int i = (it * 256 + tid) * 4;
        const int cl = i >> 7, rl = i & 127;
        *(ushort4*)&OT[(long)b * LL * DD + (long)(colg0 + cl) * LL + lr0 +
                       rl] = *(ushort4*)&tb[cl * 132 + rl];
      }
    }
  }
}

// ---------------------------------------------------------------------------
// vp transpose only: [1024][512] -> [512][1024]; slabs >= len skipped.
// grid (8, 16, 16)
// ---------------------------------------------------------------------------
__global__ __launch_bounds__(256) void k_tr(const u16* __restrict__ vp,
                                            const int* __restrict__ lens,
                                            u16* __restrict__ vpT) {
  const int b = blockIdx.z;
  const int r0 = blockIdx.y * 64, c0 = blockIdx.x * 64;
  if (r0 >= lens[b]) return;
  const u16* X = vp + (long)b * LL * DD;
  u16* O = vpT + (long)b * LL * DD;
  __shared__ u16 t[64][68];
  const int tid = threadIdx.x;
#pragma unroll
  for (int i = 0; i < 16; ++i) {
    const int idx = tid + i * 256;
    t[idx >> 6][idx & 63] = X[(long)(r0 + (idx >> 6)) * DD + c0 + (idx & 63)];
  }
  __syncthreads();
#pragma unroll
  for (int i = 0; i < 16; ++i) {
    const int idx = tid + i * 256;
    const int rr = idx >> 6, cc = idx & 63;
    O[(long)(c0 + rr) * LL + r0 + cc] = t[cc][rr];
  }
}

// ---------------------------------------------------------------------------
// distance matmuls (split), compacted + XCD-chunked 1D grid (1024):
//   [0,512): qt tiles batch-contiguous with stripe-4; then kt kept tiles
// ---------------------------------------------------------------------------
__global__ __launch_bounds__(256, 3) void k_dist_g(
    const u16* __restrict__ dist_h, const u16* __restrict__ dist_l,
    const u16* __restrict__ qT_h, const u16* __restrict__ qT_l,
    const u16* __restrict__ kT_h, const u16* __restrict__ kT_l,
    const int* __restrict__ lens, u16* __restrict__ qt_h,
    u16* __restrict__ qt_l, u16* __restrict__ kt_h, u16* __restrict__ kt_l) {
  const int flat = xcd_chunk16(blockIdx.x);
  int b, sel, bm, bn;
  if (flat < 512) {
    sel = 0;
    b = flat >> 5;
    const int r = flat & 31;
    const int s = r >> 4, inner = r & 15;
    bm = (s * 4 + (inner & 3)) * 128;
    bn = (inner >> 2) * 128;
  } else {
    int loc, rem;
    b = scan_batches(lens, flat - 512, 4, &loc, &rem);
    if (b < 0) return;
    sel = 1;
    bm = (loc >> 2) * 128;
    bn = (loc & 3) * 128;
  }
  const u16* Ah = dist_h + (long)b * LL * LL;
  const u16* Al = dist_l + (long)b * LL * LL;
  const u16* Bh = (sel ? kT_h : qT_h) + (long)b * LL * DD;
  const u16* Bl = (sel ? kT_l : qT_l) + (long)b * LL * DD;
  u16* Oh = (sel ? kt_h : qt_h) + (long)b * LL * DD;
  u16* Ol = (sel ? kt_l : qt_l) + (long)b * LL * DD;
  __shared__ __align__(16) char smem[32768];
  f32x4 acc[4][4] = {};
  core_split(Ah, Al, LL, Bh, Bl, LL, LL, bm, bn, smem, acc);
  EPI_PROLOG()
#pragma unroll
  for (int mi = 0; mi < 4; ++mi) {
    const int R0 = bm + wm + mi * 16 + ks * 4;
#pragma unroll
    for (int ni = 0; ni < 4; ++ni) {
      const int col = bn + wn + ni * 16 + fr;
#pragma unroll
      for (int j = 0; j < 4; ++j) {
        const long idx = (long)(R0 + j) * DD + col;
        const float x = acc[mi][ni][j];
        const u16 h = f2bf(x);
        Oh[idx] = h;
        Ol[idx] = f2bf(x - bf2f(h));
      }
    }
  }
}

// ---------------------------------------------------------------------------
// scores, compacted + XCD-chunked grid (1024): compute tiles first with
// stripe-4 within batch; remaining blocks zero-fill masked tiles.
// Merged K-loop (6 LDS tiles, 48KB static).
// ---------------------------------------------------------------------------
__global__ __launch_bounds__(256, 3) void k_score(
    const u16* __restrict__ qp, const u16* __restrict__ kp,
    const u16* __restrict__ qt_h, const u16* __restrict__ qt_l,
    const u16* __restrict__ kt_h, const u16* __restrict__ kt_l,
    const int* __restrict__ lens, float* __restrict__ attnF,
    u16* __restrict__ attnB) {
  const int tid = threadIdx.x;
  int loc, rem;
  int b = scan_batches(lens, xcd_chunk16(blockIdx.x), 8, &loc, &rem);
  int bm, bn;
  if (b < 0) {  // masked-tile region: zero-fill
    for (int i = 0; i < NB; ++i) {
      const int nbn = (lens[i] + 127) >> 7;
      const int c = (8 - nbn) << 3;
      if (rem < c) {
        b = i;
        const int wdt = 8 - nbn;
        bm = (rem / wdt) * 128;
        bn = (nbn + rem % wdt) * 128;
        break;
      }
      rem -= c;
    }
    if (b < 0) return;
    const long baseF = (long)b * LL * LL;
    const float4 zf = make_float4(0.f, 0.f, 0.f, 0.f);
    const ushort4 zh = {0, 0, 0, 0};
    for (int i = tid; i < 4096; i += 256) {
      const int row = i >> 5, c = (i & 31) << 2;
      const long idx = baseF + (long)(bm + row) * LL + bn + c;
      *(float4*)&attnF[idx] = zf;
      *(ushort4*)&attnB[idx] = zh;
    }
    return;
  }
  const int nbn = (lens[b] + 127) >> 7;
  {  // stripe-4: bm fastest in groups of 4
    const int S = nbn << 2;
    const int s = loc / S, inner = loc - s * S;
    bm = (s * 4 + (inner & 3)) * 128;
    bn = (inner >> 2) * 128;
  }
  const int len = lens[b];
  const long baseF = (long)b * LL * LL;
  const long od = (long)b * LL * DD;
  const u16* Ah = qt_h + od;
  const u16* Al = qt_l + od;
  const u16* Bh = kt_h + od;
  const u16* Bl = kt_l + od;
  const u16* Ap = qp + od;
  const u16* Bp = kp + od;
  __shared__ __align__(16) char smem[49152];
  char* Ash = smem;
  char* Bsh = smem + 8192;
  char* Asl = smem + 16384;
  char* Bsl = smem + 24576;
  char* Aps = smem + 32768;
  char* Bps = smem + 40960;
  const int w = tid >> 6, l = tid & 63;
  const int wm = (w >> 1) * 64, wn = (w & 1) * 64;
  const int fr = l & 15, ks = l >> 4;
  f32x4 acc[4][4] = {};
  for (int k0 = 0; k0 < DD; k0 += 32) {
    stage_tile<2>(Ah, DD, bm, k0, Ash, w, l);
    stage_tile<2>(Bh, DD, bn, k0, Bsh, w, l);
    stage_tile<2>(Al, DD, bm, k0, Asl, w, l);
    stage_tile<2>(Bl, DD, bn, k0, Bsl, w, l);
    stage_tile<2>(Ap, DD, bm, k0, Aps, w, l);
    stage_tile<2>(Bp, DD, bn, k0, Bps, w, l);
    __syncthreads();
    bf16x8 ah[4], bh[4];
#pragma unroll
    for (int i = 0; i < 4; ++i) {
      ah[i] = read_frag(Ash, wm + i * 16 + fr, ks);
      bh[i] = read_frag(Bsh, wn + i * 16 + fr, ks);
    }
#pragma unroll
    for (int mi = 0; mi < 4; ++mi)
#pragma unroll
      for (int ni = 0; ni < 4; ++ni)
        acc[mi][ni] = __builtin_amdgcn_mfma_f32_16x16x32_bf16(
            ah[mi], bh[ni], acc[mi][ni], 0, 0, 0);
    bf16x8 bl[4];
#pragma unroll
    for (int ni = 0; ni < 4; ++ni)
      bl[ni] = read_frag(Bsl, wn + ni * 16 + fr, ks);
#pragma unroll
    for (int mi = 0; mi < 4; ++mi)
#pragma unroll
      for (int ni = 0; ni < 4; ++ni)
        acc[mi][ni] = __builtin_amdgcn_mfma_f32_16x16x32_bf16(
            ah[mi], bl[ni], acc[mi][ni], 0, 0, 0);
    bf16x8 al[4];
#pragma unroll
    for (int mi = 0; mi < 4; ++mi)
      al[mi] = read_frag(Asl, wm + mi * 16 + fr, ks);
#pragma unroll
    for (int mi = 0; mi < 4; ++mi)
#pragma unroll
      for (int ni = 0; ni < 4; ++ni)
        acc[mi][ni] = __builtin_amdgcn_mfma_f32_16x16x32_bf16(
            al[mi], bh[ni], acc[mi][ni], 0, 0, 0);
    bf16x8 ap[4], bp[4];
#pragma unroll
    for (int i = 0; i < 4; ++i) {
      ap[i] = read_frag(Aps, wm + i * 16 + fr, ks);
      bp[i] = read_frag(Bps, wn + i * 16 + fr, ks);
    }
#pragma unroll
    for (int mi = 0; mi < 4; ++mi)
#pragma unroll
      for (int ni = 0; ni < 4; ++ni)
        acc[mi][ni] = __builtin_amdgcn_mfma_f32_16x16x32_bf16(
            ap[mi], bp[ni], acc[mi][ni], 0, 0, 0);
    __syncthreads();
  }
  const float invt = 0.04419417382415922f;  // 1/sqrt(512)
#pragma unroll
  for (int mi = 0; mi < 4; ++mi) {
    const int R0 = bm + wm + mi * 16 + ks * 4;
#pragma unroll
    for (int ni = 0; ni < 4; ++ni) {
      const int col = bn + wn + ni * 16 + fr;
      const float m = (col < len) ? 1.0f : 0.0f;
#pragma unroll
      for (int j = 0; j < 4; ++j) {
        const float s = tanhf(acc[mi][ni][j] * invt * m) * m;
        const long idx = baseF + (long)(R0 + j) * LL + col;
        attnF[idx] = s;
        attnB[idx] = f2bf(s);
      }
    }
  }
}

// ---------------------------------------------------------------------------
// PV: out0 = attn * vp (via vpT), K truncated to ceil(len/32)*32.
// XCD-chunked grid (512), batch-contiguous, bn fastest.
// ---------------------------------------------------------------------------
__global__ __launch_bounds__(256, 3) void k_pv(const u16* __restrict__ attnB,
                                               const u16* __restrict__ vpT,
                                               const int* __restrict__ lens,
                                               u16* __restrict__ out0) {
  const int flat = xcd_chunk16(blockIdx.x);
  const int b = flat >> 5;
  const int r = flat & 31;
  const int bm = (r >> 2) * 128, bn = (r & 3) * 128;
  const int Kt = ((lens[b] + 31) >> 5) << 5;
  __shared__ __align__(16) char smem[16384];
  f32x4 acc[4][4] = {};
  core_plain(attnB + (long)b * LL * LL, LL, vpT + (long)b * LL * DD, LL, Kt,
             bm, bn, smem, acc);
  u16* C = out0 + (long)b * LL * DD;
  EPI_PROLOG()
#pragma unroll
  for (int mi = 0; mi < 4; ++mi) {
    const int R0 = bm + wm + mi * 16 + ks * 4;
#pragma unroll
    for (int ni = 0; ni < 4; ++ni) {
      const int col = bn + wn + ni * 16 + fr;
#pragma unroll
      for (int j = 0; j < 4; ++j)
        C[(long)(R0 + j) * DD + col] = f2bf(acc[mi][ni][j]);
    }
  }
}

// ---------------------------------------------------------------------------
// Fused FC + residual + LayerNorm. 64 rows x full 512 cols. grid (256)
// ---------------------------------------------------------------------------
__global__ __launch_bounds__(256, 2) void k_fcln(
    const u16* __restrict__ out0, const u16* __restrict__ Wfc_h,
    const float* __restrict__ q, const float* __restrict__ gamma,
    const float* __restrict__ beta, float* __restrict__ outO) {
  __shared__ __align__(16) char smem[36864];  // As 4KB + Bs 32KB
  __shared__ float red[2][64][5];
  const int tid = threadIdx.x, w = tid >> 6, l = tid & 63;
  const int wn = w * 128;
  const int fr = l & 15, ks = l >> 4;
  const int bm = blockIdx.x * 64;
  char* As = smem;
  char* Bs = smem + 4096;
  f32x4 acc[4][8] = {};
  for (int k0 = 0; k0 < DD; k0 += 32) {
    stage_tile<1>(out0, DD, bm, k0, As, w, l);
    stage_tile<8>(Wfc_h, DD, 0, k0, Bs, w, l);
    __syncthreads();
    bf16x8 af[4], bg[8];
#pragma unroll
    for (int mi = 0; mi < 4; ++mi) af[mi] = read_frag(As, mi * 16 + fr, ks);
#pragma unroll
    for (int ni = 0; ni < 8; ++ni)
      bg[ni] = read_frag(Bs, wn + ni * 16 + fr, ks);
#pragma unroll
    for (int mi = 0; mi < 4; ++mi)
#pragma unroll
      for (int ni = 0; ni < 8; ++ni)
        acc[mi][ni] = __builtin_amdgcn_mfma_f32_16x16x32_bf16(
            af[mi], bg[ni], acc[mi][ni], 0, 0, 0);
    __syncthreads();
  }
  float p1[4][4], p2[4][4];
#pragma unroll
  for (int mi = 0; mi < 4; ++mi)
#pragma unroll
    for (int j = 0; j < 4; ++j) {
      p1[mi][j] = 0.0f;
      p2[mi][j] = 0.0f;
    }
#pragma unroll
  for (int mi = 0; mi < 4; ++mi) {
    const int r = mi * 16 + ks * 4;
#pragma unroll
    for (int ni = 0; ni < 8; ++ni) {
      const int col = wn + ni * 16 + fr;
#pragma unroll
      for (int j = 0; j < 4; ++j) {
        const float val = acc[mi][ni][j] + q[(long)(bm + r + j) * DD + col];
        acc[mi][ni][j] = val;
        p1[mi][j] += val;
        p2[mi][j] += val * val;
      }
    }
  }
#pragma unroll
  for (int off = 1; off < 16; off <<= 1) {
#pragma unroll
    for (int mi = 0; mi < 4; ++mi)
#pragma unroll
      for (int j = 0; j < 4; ++j) {
        p1[mi][j] += __shfl_xor(p1[mi][j], off);
        p2[mi][j] += __shfl_xor(p2[mi][j], off);
      }
  }
  if (fr == 0) {
#pragma unroll
    for (int mi = 0; mi < 4; ++mi)
#pragma unroll
      for (int j = 0; j < 4; ++j) {
        red[0][mi * 16 + ks * 4 + j][w] = p1[mi][j];
        red[1][mi * 16 + ks * 4 + j][w] = p2[mi][j];
      }
  }
  __syncthreads();
#pragma unroll
  for (int mi = 0; mi < 4; ++mi) {
#pragma unroll
    for (int j = 0; j < 4; ++j) {
      const int r = mi * 16 + ks * 4 + j;
      const float s1 =
          red[0][r][0] + red[0][r][1] + red[0][r][2] + red[0][r][3];
      const float s2 =
          red[1][r][0] + red[1][r][1] + red[1][r][2] + red[1][r][3];
      const float mu = s1 * (1.0f / DD);
      const float rs = rsqrtf(s2 * (1.0f / DD) - mu * mu + 1e-6f);
#pragma unroll
      for (int ni = 0; ni < 8; ++ni) {
        const int col = wn + ni * 16 + fr;
        outO[(long)(bm + r) * DD + col] =
            (acc[mi][ni][j] - mu) * rs * gamma[col] + beta[col];
      }
    }
  }
}

// ---------------------------------------------------------------------------
extern "C" void kernel_launch(void* const* d_in, const int* in_sizes, int n_in,
                              void* d_out, int out_size, void* d_ws,
                              size_t ws_size, hipStream_t stream) {
  const float* q = (const float*)d_in[0];
  const float* k = (const float*)d_in[1];
  const float* v = (const float*)d_in[2];
  const int* lens = (const int*)d_in[3];
  const float* dist = (const float*)d_in[4];
  const float* Wq = (const float*)d_in[5];
  const float* Wk = (const float*)d_in[6];
  const float* Wv = (const float*)d_in[7];
  const float* Wqt = (const float*)d_in[8];
  const float* Wkt = (const float*)d_in[9];
  const float* Wfc = (const float*)d_in[10];
  const float* gamma = (const float*)d_in[11];
  const float* beta = (const float*)d_in[12];

  char* W = (char*)d_ws;
  const size_t SB = 16777216;  // bytes of one bf16 [16384][512] buffer
  u16* q_hi = (u16*)(W + 0 * SB);    // reused later as qt_h
  u16* q_lo = (u16*)(W + 1 * SB);    // reused later as qt_l
  u16* k_hi = (u16*)(W + 2 * SB);    // reused later as kt_h
  u16* k_lo = (u16*)(W + 3 * SB);    // reused later as kt_l
  u16* v_hi = (u16*)(W + 4 * SB);    // reused later as vpT
  u16* dist_h = (u16*)(W + 5 * SB);  // 2SB; reused later as attnB
  u16* dist_l = (u16*)(W + 7 * SB);  // 2SB
  u16* qp_bf = (u16*)(W + 9 * SB);   // reused later as out0
  u16* kp_bf = (u16*)(W + 10 * SB);
  u16* vp_bf = (u16*)(W + 11 * SB);
  u16* qT_h = (u16*)(W + 16 * SB);   // written transposed by k_proj_t
  u16* qT_l = (u16*)(W + 17 * SB);
  u16* kT_h = (u16*)(W + 18 * SB);
  u16* kT_l = (u16*)(W + 19 * SB);
  char* WB = W + 20 * SB;
  const size_t WS = 524288;
  u16* Wq_h = (u16*)(WB + 0 * WS);
  u16* Wk_h = (u16*)(WB + 1 * WS);
  u16* Wv_h = (u16*)(WB + 2 * WS);
  u16* Wfc_h = (u16*)(WB + 3 * WS);
  u16* Wqt_h = (u16*)(WB + 4 * WS);
  u16* Wqt_l = (u16*)(WB + 5 * WS);
  u16* Wkt_h = (u16*)(WB + 6 * WS);
  u16* Wkt_l = (u16*)(WB + 7 * WS);
  // aliases (lifetimes disjoint, stream-ordered)
  u16* qt_h = q_hi;
  u16* qt_l = q_lo;
  u16* kt_h = k_hi;
  u16* kt_l = k_lo;
  u16* vpT = v_hi;
  u16* attnB = dist_h;
  u16* out0 = qp_bf;

  float* outO = (float*)d_out;
  float* attnF = outO + NLD;

  dim3 blk(256);
  k_split3<<<dim3(1024, 1, 3), blk, 0, stream>>>(q, k, v, q_hi, q_lo, k_hi,
                                                 k_lo, v_hi);
  k_splitd<<<4096, blk, 0, stream>>>(dist, dist_h, dist_l);
  k_splitw<<<dim3(256, 1, 6), blk, 0, stream>>>(Wq, Wk, Wv, Wfc, Wqt, Wkt,
                                                Wq_h, Wk_h, Wv_h, Wfc_h,
                                                Wqt_h, Wqt_l, Wkt_h, Wkt_l);

  k_proj_p<<<1536, blk, 0, stream>>>(q_hi, k_hi, v_hi, Wq_h, Wk_h, Wv_h, lens,
                                     qp_bf, kp_bf, vp_bf);
  k_proj_t<<<dim3(4, 128, 2), blk, 0, stream>>>(q_hi, q_lo, k_hi, k_lo, Wqt_h,
                                                Wqt_l, Wkt_h, Wkt_l, qT_h,
                                                qT_l, kT_h, kT_l);
  k_tr<<<dim3(8, 16, 16), blk, 0, stream>>>(vp_bf, lens, vpT);
  k_dist_g<<<1024, blk, 0, stream>>>(dist_h, dist_l, qT_h, qT_l, kT_h, kT_l,
                                     lens, qt_h, qt_l, kt_h, kt_l);
  k_score<<<1024, blk, 0, stream>>>(qp_bf, kp_bf, qt_h, qt_l, kt_h, kt_l,
                                    lens, attnF, attnB);
  k_pv<<<512, blk, 0, stream>>>(attnB, vpT, lens, out0);
  k_fcln<<<256, blk, 0, stream>>>(out0, Wfc_h, q, gamma, beta, outO);
}